// Round 1
// baseline (7689.758 us; speedup 1.0000x reference)
//
#include <hip/hip_runtime.h>
#include <math.h>

#define TT 1024
#define BB 8
#define EE 512
#define HH 8
#define DD 64
#define MM (TT*BB)        // 8192 rows (t*B + b)
#define NQKV (3*EE)       // 1536
#define SCALEF 0.125f     // D^-0.5 = 1/8

// ---------------------------------------------------------------------------
// Complex GEMM:  Yr = Xr*Wr^T - Xi*Wi^T + br ;  Yi = Xi*Wr^T + Xr*Wi^T + bi
// X: (M,K) row-major, W: (N,K) row-major, Y: (M,N) row-major.
// Block tile 64x64, 256 threads, 4x4 microtile, K-tile 16.
// ---------------------------------------------------------------------------
__global__ __launch_bounds__(256) void gemm_cplx(
    const float* __restrict__ Xr, const float* __restrict__ Xi,
    const float* __restrict__ Wr, const float* __restrict__ Wi,
    const float* __restrict__ biasr, const float* __restrict__ biasi,
    float* __restrict__ Yr, float* __restrict__ Yi,
    int N, int K)
{
    __shared__ float Ar[16][64];
    __shared__ float Ai[16][64];
    __shared__ float Br[16][64];
    __shared__ float Bi[16][64];

    const int tid = threadIdx.x;
    const int m0 = blockIdx.y * 64;
    const int n0 = blockIdx.x * 64;
    const int tx = tid & 15;          // output col group
    const int ty = tid >> 4;          // output row group
    const int lm = tid & 63;          // staging row
    const int kq = tid >> 6;          // staging k-quad (0..3)

    float accr[4][4] = {};
    float acci[4][4] = {};

    for (int k0 = 0; k0 < K; k0 += 16) {
        __syncthreads();
        // stage A (X tile) as [kk][m]
        {
            const size_t off = (size_t)(m0 + lm) * K + k0 + kq * 4;
            const float4 xr = *(const float4*)(Xr + off);
            const float4 xi = *(const float4*)(Xi + off);
            Ar[kq*4+0][lm] = xr.x; Ar[kq*4+1][lm] = xr.y;
            Ar[kq*4+2][lm] = xr.z; Ar[kq*4+3][lm] = xr.w;
            Ai[kq*4+0][lm] = xi.x; Ai[kq*4+1][lm] = xi.y;
            Ai[kq*4+2][lm] = xi.z; Ai[kq*4+3][lm] = xi.w;
        }
        // stage B (W tile) as [kk][n]
        {
            const size_t off = (size_t)(n0 + lm) * K + k0 + kq * 4;
            const float4 wr = *(const float4*)(Wr + off);
            const float4 wi = *(const float4*)(Wi + off);
            Br[kq*4+0][lm] = wr.x; Br[kq*4+1][lm] = wr.y;
            Br[kq*4+2][lm] = wr.z; Br[kq*4+3][lm] = wr.w;
            Bi[kq*4+0][lm] = wi.x; Bi[kq*4+1][lm] = wi.y;
            Bi[kq*4+2][lm] = wi.z; Bi[kq*4+3][lm] = wi.w;
        }
        __syncthreads();
        #pragma unroll
        for (int kk = 0; kk < 16; ++kk) {
            const float4 arv = *(const float4*)&Ar[kk][ty*4];
            const float4 aiv = *(const float4*)&Ai[kk][ty*4];
            const float4 brv = *(const float4*)&Br[kk][tx*4];
            const float4 biv = *(const float4*)&Bi[kk][tx*4];
            const float a_r[4] = {arv.x, arv.y, arv.z, arv.w};
            const float a_i[4] = {aiv.x, aiv.y, aiv.z, aiv.w};
            const float b_r[4] = {brv.x, brv.y, brv.z, brv.w};
            const float b_i[4] = {biv.x, biv.y, biv.z, biv.w};
            #pragma unroll
            for (int i = 0; i < 4; ++i) {
                #pragma unroll
                for (int j = 0; j < 4; ++j) {
                    accr[i][j] = fmaf(a_r[i],  b_r[j], accr[i][j]);
                    accr[i][j] = fmaf(-a_i[i], b_i[j], accr[i][j]);
                    acci[i][j] = fmaf(a_i[i],  b_r[j], acci[i][j]);
                    acci[i][j] = fmaf(a_r[i],  b_i[j], acci[i][j]);
                }
            }
        }
    }

    // epilogue: add bias, store
    const int nc = n0 + tx * 4;
    const float4 bR = *(const float4*)(biasr + nc);
    const float4 bI = *(const float4*)(biasi + nc);
    #pragma unroll
    for (int i = 0; i < 4; ++i) {
        const size_t row = (size_t)(m0 + ty * 4 + i);
        float4 oR, oI;
        oR.x = accr[i][0] + bR.x; oR.y = accr[i][1] + bR.y;
        oR.z = accr[i][2] + bR.z; oR.w = accr[i][3] + bR.w;
        oI.x = acci[i][0] + bI.x; oI.y = acci[i][1] + bI.y;
        oI.z = acci[i][2] + bI.z; oI.w = acci[i][3] + bI.w;
        *(float4*)(Yr + row * N + nc) = oR;
        *(float4*)(Yi + row * N + nc) = oI;
    }
}

// ---------------------------------------------------------------------------
// Fused complex attention for one (b, h, 16-row q tile).
// qkv layout: [t*B+b][3E] with q = cols 0..E, k = E..2E, v = 2E..3E.
// Writes attn (pre-out-proj) in [t*B+b][E] layout and atomically accumulates
// aw/H into aw_out[2][B][T][T] (pre-zeroed).
// ---------------------------------------------------------------------------
__global__ __launch_bounds__(256) void attn_fused(
    const float* __restrict__ qkv_r, const float* __restrict__ qkv_i,
    float* __restrict__ attn_r, float* __restrict__ attn_i,
    float* __restrict__ aw_out)
{
    __shared__ float S[2][16][TT];    // 128 KiB score/aw tiles (r and i parts)
    __shared__ float Q[2][16][68];    // padded to kill bank conflicts

    const int qt = blockIdx.x, h = blockIdx.y, b = blockIdx.z;
    const int t0 = qt * 16;
    const int tid = threadIdx.x;
    const int r = tid >> 4;           // 0..15 q-row within tile
    const int c = tid & 15;           // 0..15 lane within row group

    // stage Q tile (both parts)
    {
        const int d4 = c * 4;
        const size_t base = ((size_t)(t0 + r) * BB + b) * NQKV + h * DD + d4;
        *(float4*)&Q[0][r][d4] = *(const float4*)(qkv_r + base);
        *(float4*)&Q[1][r][d4] = *(const float4*)(qkv_i + base);
    }
    __syncthreads();

    // ---- scores: S_r = (qr.kr + qi.ki)*scale, S_i = (qi.kr - qr.ki)*scale
    for (int c0 = 0; c0 < TT; c0 += 16) {
        const int key = c0 + c;
        const size_t kbase = ((size_t)key * BB + b) * NQKV + EE + h * DD;
        const float* kr = qkv_r + kbase;
        const float* ki = qkv_i + kbase;
        float sr = 0.f, si = 0.f;
        #pragma unroll
        for (int d = 0; d < DD; d += 4) {
            const float4 k_r = *(const float4*)(kr + d);
            const float4 k_i = *(const float4*)(ki + d);
            const float4 q_r = *(const float4*)&Q[0][r][d];
            const float4 q_i = *(const float4*)&Q[1][r][d];
            sr = fmaf(q_r.x, k_r.x, sr); sr = fmaf(q_r.y, k_r.y, sr);
            sr = fmaf(q_r.z, k_r.z, sr); sr = fmaf(q_r.w, k_r.w, sr);
            sr = fmaf(q_i.x, k_i.x, sr); sr = fmaf(q_i.y, k_i.y, sr);
            sr = fmaf(q_i.z, k_i.z, sr); sr = fmaf(q_i.w, k_i.w, sr);
            si = fmaf(q_i.x, k_r.x, si); si = fmaf(q_i.y, k_r.y, si);
            si = fmaf(q_i.z, k_r.z, si); si = fmaf(q_i.w, k_r.w, si);
            si = fmaf(-q_r.x, k_i.x, si); si = fmaf(-q_r.y, k_i.y, si);
            si = fmaf(-q_r.z, k_i.z, si); si = fmaf(-q_r.w, k_i.w, si);
        }
        S[0][r][key] = sr * SCALEF;
        S[1][r][key] = si * SCALEF;
    }
    __syncthreads();

    // ---- exact softmax per row for both parts; accumulate head-avg output
    #pragma unroll
    for (int p = 0; p < 2; ++p) {
        float m = -1e30f;
        for (int j = c; j < TT; j += 16) m = fmaxf(m, S[p][r][j]);
        #pragma unroll
        for (int off = 8; off; off >>= 1) m = fmaxf(m, __shfl_xor(m, off, 16));
        float sum = 0.f;
        for (int j = c; j < TT; j += 16) {
            const float e = __expf(S[p][r][j] - m);
            S[p][r][j] = e;
            sum += e;
        }
        #pragma unroll
        for (int off = 8; off; off >>= 1) sum += __shfl_xor(sum, off, 16);
        const float inv = 1.0f / sum;
        float* awp = aw_out + (size_t)p * ((size_t)BB * TT * TT)
                   + ((size_t)b * TT + (t0 + r)) * TT;
        for (int j = c; j < TT; j += 16) {
            const float a = S[p][r][j] * inv;
            S[p][r][j] = a;
            atomicAdd(awp + j, a * 0.125f);
        }
    }
    __syncthreads();

    // ---- PV: attn_r = aw_r@v_r + aw_i@v_i ; attn_i = aw_i@v_r - aw_r@v_i
    {
        const int d4 = c * 4;
        float4 aR = {0.f, 0.f, 0.f, 0.f};
        float4 aI = {0.f, 0.f, 0.f, 0.f};
        for (int key = 0; key < TT; ++key) {
            const size_t vb = ((size_t)key * BB + b) * NQKV + 2 * EE + h * DD + d4;
            const float4 vr = *(const float4*)(qkv_r + vb);
            const float4 vi = *(const float4*)(qkv_i + vb);
            const float ar = S[0][r][key];
            const float ai = S[1][r][key];
            aR.x = fmaf(ar, vr.x, aR.x); aR.x = fmaf(ai, vi.x, aR.x);
            aR.y = fmaf(ar, vr.y, aR.y); aR.y = fmaf(ai, vi.y, aR.y);
            aR.z = fmaf(ar, vr.z, aR.z); aR.z = fmaf(ai, vi.z, aR.z);
            aR.w = fmaf(ar, vr.w, aR.w); aR.w = fmaf(ai, vi.w, aR.w);
            aI.x = fmaf(ai, vr.x, aI.x); aI.x = fmaf(-ar, vi.x, aI.x);
            aI.y = fmaf(ai, vr.y, aI.y); aI.y = fmaf(-ar, vi.y, aI.y);
            aI.z = fmaf(ai, vr.z, aI.z); aI.z = fmaf(-ar, vi.z, aI.z);
            aI.w = fmaf(ai, vr.w, aI.w); aI.w = fmaf(-ar, vi.w, aI.w);
        }
        const size_t ob = ((size_t)(t0 + r) * BB + b) * EE + h * DD + d4;
        *(float4*)(attn_r + ob) = aR;
        *(float4*)(attn_i + ob) = aI;
    }
}

// ---------------------------------------------------------------------------
extern "C" void kernel_launch(void* const* d_in, const int* in_sizes, int n_in,
                              void* d_out, int out_size, void* d_ws, size_t ws_size,
                              hipStream_t stream)
{
    const float* query_r = (const float*)d_in[0];
    const float* query_i = (const float*)d_in[1];
    const float* W_qkv_r = (const float*)d_in[2];
    const float* W_qkv_i = (const float*)d_in[3];
    const float* b_qkv_r = (const float*)d_in[4];
    const float* b_qkv_i = (const float*)d_in[5];
    const float* W_out_r = (const float*)d_in[6];
    const float* W_out_i = (const float*)d_in[7];
    const float* b_out_r = (const float*)d_in[8];
    const float* b_out_i = (const float*)d_in[9];

    float* ws = (float*)d_ws;
    float* qkv_r  = ws;                                  // 12,582,912 floats
    float* qkv_i  = qkv_r  + (size_t)MM * NQKV;
    float* attn_r = qkv_i  + (size_t)MM * NQKV;          //  4,194,304 floats
    float* attn_i = attn_r + (size_t)MM * EE;
    // total ws use: 134,217,728 bytes

    float* out   = (float*)d_out;
    float* out_r = out;                                  // [T,B,E]
    float* out_i = out + (size_t)MM * EE;
    float* aw    = out + 2 * (size_t)MM * EE;            // [2,B,T,T]

    // aw is accumulated atomically -> zero it each call
    hipMemsetAsync(aw, 0, (size_t)2 * BB * TT * TT * sizeof(float), stream);

    // QKV projection (complex)
    {
        dim3 grid(NQKV / 64, MM / 64);
        gemm_cplx<<<grid, dim3(256), 0, stream>>>(
            query_r, query_i, W_qkv_r, W_qkv_i, b_qkv_r, b_qkv_i,
            qkv_r, qkv_i, NQKV, EE);
    }
    // fused attention
    {
        dim3 grid(TT / 16, HH, BB);
        attn_fused<<<grid, dim3(256), 0, stream>>>(qkv_r, qkv_i, attn_r, attn_i, aw);
    }
    // output projection (complex)
    {
        dim3 grid(EE / 64, MM / 64);
        gemm_cplx<<<grid, dim3(256), 0, stream>>>(
            attn_r, attn_i, W_out_r, W_out_i, b_out_r, b_out_i,
            out_r, out_i, EE, EE);
    }
}

// Round 2
// 1833.546 us; speedup vs baseline: 4.1939x; 4.1939x over previous
//
#include <hip/hip_runtime.h>
#include <math.h>

#define TT 1024
#define BB 8
#define EE 512
#define HH 8
#define DD 64
#define MM (TT*BB)        // 8192 rows (t*B + b)
#define NQKV (3*EE)       // 1536
#define SCALEF 0.125f     // D^-0.5 = 1/8

typedef _Float16 f16;
typedef f16 f16x8 __attribute__((ext_vector_type(8)));
typedef f16 f16x4 __attribute__((ext_vector_type(4)));
typedef float f32x4 __attribute__((ext_vector_type(4)));

#define MFMA16 __builtin_amdgcn_mfma_f32_16x16x32_f16

__device__ inline f16x8 cvt8(float4 a, float4 b) {
    f16x8 r;
    r[0]=(f16)a.x; r[1]=(f16)a.y; r[2]=(f16)a.z; r[3]=(f16)a.w;
    r[4]=(f16)b.x; r[5]=(f16)b.y; r[6]=(f16)b.z; r[7]=(f16)b.w;
    return r;
}
__device__ inline f16x4 cvt4(float4 a) {
    f16x4 r; r[0]=(f16)a.x; r[1]=(f16)a.y; r[2]=(f16)a.z; r[3]=(f16)a.w;
    return r;
}

// ---------------------------------------------------------------------------
// Complex GEMM (fp32 VALU), unchanged from round 1.
// ---------------------------------------------------------------------------
__global__ __launch_bounds__(256) void gemm_cplx(
    const float* __restrict__ Xr, const float* __restrict__ Xi,
    const float* __restrict__ Wr, const float* __restrict__ Wi,
    const float* __restrict__ biasr, const float* __restrict__ biasi,
    float* __restrict__ Yr, float* __restrict__ Yi,
    int N, int K)
{
    __shared__ float Ar[16][64];
    __shared__ float Ai[16][64];
    __shared__ float Br[16][64];
    __shared__ float Bi[16][64];

    const int tid = threadIdx.x;
    const int m0 = blockIdx.y * 64;
    const int n0 = blockIdx.x * 64;
    const int tx = tid & 15;
    const int ty = tid >> 4;
    const int lm = tid & 63;
    const int kq = tid >> 6;

    float accr[4][4] = {};
    float acci[4][4] = {};

    for (int k0 = 0; k0 < K; k0 += 16) {
        __syncthreads();
        {
            const size_t off = (size_t)(m0 + lm) * K + k0 + kq * 4;
            const float4 xr = *(const float4*)(Xr + off);
            const float4 xi = *(const float4*)(Xi + off);
            Ar[kq*4+0][lm] = xr.x; Ar[kq*4+1][lm] = xr.y;
            Ar[kq*4+2][lm] = xr.z; Ar[kq*4+3][lm] = xr.w;
            Ai[kq*4+0][lm] = xi.x; Ai[kq*4+1][lm] = xi.y;
            Ai[kq*4+2][lm] = xi.z; Ai[kq*4+3][lm] = xi.w;
        }
        {
            const size_t off = (size_t)(n0 + lm) * K + k0 + kq * 4;
            const float4 wr = *(const float4*)(Wr + off);
            const float4 wi = *(const float4*)(Wi + off);
            Br[kq*4+0][lm] = wr.x; Br[kq*4+1][lm] = wr.y;
            Br[kq*4+2][lm] = wr.z; Br[kq*4+3][lm] = wr.w;
            Bi[kq*4+0][lm] = wi.x; Bi[kq*4+1][lm] = wi.y;
            Bi[kq*4+2][lm] = wi.z; Bi[kq*4+3][lm] = wi.w;
        }
        __syncthreads();
        #pragma unroll
        for (int kk = 0; kk < 16; ++kk) {
            const float4 arv = *(const float4*)&Ar[kk][ty*4];
            const float4 aiv = *(const float4*)&Ai[kk][ty*4];
            const float4 brv = *(const float4*)&Br[kk][tx*4];
            const float4 biv = *(const float4*)&Bi[kk][tx*4];
            const float a_r[4] = {arv.x, arv.y, arv.z, arv.w};
            const float a_i[4] = {aiv.x, aiv.y, aiv.z, aiv.w};
            const float b_r[4] = {brv.x, brv.y, brv.z, brv.w};
            const float b_i[4] = {biv.x, biv.y, biv.z, biv.w};
            #pragma unroll
            for (int i = 0; i < 4; ++i) {
                #pragma unroll
                for (int j = 0; j < 4; ++j) {
                    accr[i][j] = fmaf(a_r[i],  b_r[j], accr[i][j]);
                    accr[i][j] = fmaf(-a_i[i], b_i[j], accr[i][j]);
                    acci[i][j] = fmaf(a_i[i],  b_r[j], acci[i][j]);
                    acci[i][j] = fmaf(a_r[i],  b_i[j], acci[i][j]);
                }
            }
        }
    }

    const int nc = n0 + tx * 4;
    const float4 bR = *(const float4*)(biasr + nc);
    const float4 bI = *(const float4*)(biasi + nc);
    #pragma unroll
    for (int i = 0; i < 4; ++i) {
        const size_t row = (size_t)(m0 + ty * 4 + i);
        float4 oR, oI;
        oR.x = accr[i][0] + bR.x; oR.y = accr[i][1] + bR.y;
        oR.z = accr[i][2] + bR.z; oR.w = accr[i][3] + bR.w;
        oI.x = acci[i][0] + bI.x; oI.y = acci[i][1] + bI.y;
        oI.z = acci[i][2] + bI.z; oI.w = acci[i][3] + bI.w;
        *(float4*)(Yr + row * N + nc) = oR;
        *(float4*)(Yi + row * N + nc) = oI;
    }
}

// ---------------------------------------------------------------------------
// MFMA f16 fused complex attention.
// Block = (b, h, 16 q-rows), 256 threads = 4 waves.
// Phase A: stage K chunks (64 keys) in swizzled LDS f16, MFMA scores -> S fp32.
// Phase B: exact softmax on S (fp32), atomicAdd head-averaged aw.
// Phase C: stage V chunks transposed (d-major) in swizzled LDS f16,
//          MFMA attn^T = V^T . AW^T (k-map-consistent fragments).
// ---------------------------------------------------------------------------
__global__ __launch_bounds__(256) void attn_mfma(
    const float* __restrict__ qkv_r, const float* __restrict__ qkv_i,
    float* __restrict__ attn_r, float* __restrict__ attn_i,
    float* __restrict__ aw_out)
{
    __shared__ float S[2][16][1028];                               // 131584 B
    __shared__ __attribute__((aligned(16))) f16 KV[2][64][64];     //  16384 B

    const int qt = blockIdx.x, h = blockIdx.y, b = blockIdx.z;
    const int t0 = qt * 16;
    const int tid = threadIdx.x;
    const int wave = tid >> 6;
    const int lane = tid & 63;
    const int g = lane >> 4;          // lane group 0..3 -> k = g*8 + j
    const int c16 = lane & 15;

    // ---- Q fragments (A operand: row = c16, k = g*8+j), held in registers
    const float* qrp = qkv_r + ((size_t)(t0 + c16) * BB + b) * NQKV + h * DD;
    const float* qip = qkv_i + ((size_t)(t0 + c16) * BB + b) * NQKV + h * DD;
    const f16x8 qr0 = cvt8(*(const float4*)(qrp + g*8),      *(const float4*)(qrp + g*8 + 4));
    const f16x8 qr1 = cvt8(*(const float4*)(qrp + 32 + g*8), *(const float4*)(qrp + 36 + g*8));
    const f16x8 qi0 = cvt8(*(const float4*)(qip + g*8),      *(const float4*)(qip + g*8 + 4));
    const f16x8 qi1 = cvt8(*(const float4*)(qip + 32 + g*8), *(const float4*)(qip + 36 + g*8));
    const f16x8 nqr0 = -qr0;
    const f16x8 nqr1 = -qr1;

    // ================= Phase A: scores =================
    for (int ch = 0; ch < 16; ++ch) {
        // stage K chunk: KV[p][key][d] f16, swizzled byte ^= (key&7)<<4
        #pragma unroll
        for (int i = 0; i < 8; ++i) {
            const int flat = i * 256 + tid;
            const int f4  = flat & 7;
            const int key = (flat >> 3) & 63;
            const int p   = (flat >> 9) & 1;
            const int dh  = flat >> 10;
            const float* src = (p ? qkv_i : qkv_r)
                + ((size_t)(ch*64 + key) * BB + b) * NQKV + EE + h * DD + dh*32 + f4*4;
            const float4 v = *(const float4*)src;
            const int byte = (key*128 + dh*64 + f4*8) ^ ((key & 7) << 4);
            *(f16x4*)((char*)&KV[p][0][0] + byte) = cvt4(v);
        }
        __syncthreads();
        // wave computes its 16-key tile
        {
            const int krow = wave * 16 + c16;           // key within chunk
            const int sw = (krow & 7) << 4;
            const char* k0 = (const char*)&KV[0][0][0];
            const char* k1 = (const char*)&KV[1][0][0];
            const f16x8 kr0 = *(const f16x8*)(k0 + ((krow*128 +  0 + g*16) ^ sw));
            const f16x8 kr1 = *(const f16x8*)(k0 + ((krow*128 + 64 + g*16) ^ sw));
            const f16x8 ki0 = *(const f16x8*)(k1 + ((krow*128 +  0 + g*16) ^ sw));
            const f16x8 ki1 = *(const f16x8*)(k1 + ((krow*128 + 64 + g*16) ^ sw));
            f32x4 ar = {0.f,0.f,0.f,0.f}, ai = {0.f,0.f,0.f,0.f};
            ar = MFMA16(qr0, kr0, ar, 0,0,0);
            ar = MFMA16(qr1, kr1, ar, 0,0,0);
            ar = MFMA16(qi0, ki0, ar, 0,0,0);
            ar = MFMA16(qi1, ki1, ar, 0,0,0);
            ai = MFMA16(qi0, kr0, ai, 0,0,0);
            ai = MFMA16(qi1, kr1, ai, 0,0,0);
            ai = MFMA16(nqr0, ki0, ai, 0,0,0);
            ai = MFMA16(nqr1, ki1, ai, 0,0,0);
            const int kcol = ch * 64 + krow;
            #pragma unroll
            for (int rg = 0; rg < 4; ++rg) {            // C/D: row=(g*4+rg), col=c16
                S[0][g*4 + rg][kcol] = ar[rg] * SCALEF;
                S[1][g*4 + rg][kcol] = ai[rg] * SCALEF;
            }
        }
        __syncthreads();
    }

    // ================= Phase B: softmax + aw average =================
    {
        const int r = tid >> 4;
        const int c = tid & 15;
        #pragma unroll
        for (int p = 0; p < 2; ++p) {
            float m = -1e30f;
            for (int j = c; j < TT; j += 16) m = fmaxf(m, S[p][r][j]);
            #pragma unroll
            for (int off = 8; off; off >>= 1) m = fmaxf(m, __shfl_xor(m, off, 16));
            float sum = 0.f;
            for (int j = c; j < TT; j += 16) {
                const float e = __expf(S[p][r][j] - m);
                S[p][r][j] = e;
                sum += e;
            }
            #pragma unroll
            for (int off = 8; off; off >>= 1) sum += __shfl_xor(sum, off, 16);
            const float inv = 1.0f / sum;
            float* awp = aw_out + (size_t)p * ((size_t)BB * TT * TT)
                       + ((size_t)b * TT + (t0 + r)) * TT;
            for (int j = c; j < TT; j += 16) {
                const float a = S[p][r][j] * inv;
                S[p][r][j] = a;
                atomicAdd(awp + j, a * 0.125f);
            }
        }
    }

    // ================= Phase C: PV (transposed) =================
    f32x4 pr = {0.f,0.f,0.f,0.f}, pi = {0.f,0.f,0.f,0.f};
    for (int ch = 0; ch < 16; ++ch) {
        // stage V chunk transposed: KV[p][d][key] f16, swizzled byte ^= (d&7)<<4
        #pragma unroll
        for (int i = 0; i < 8; ++i) {
            const int flat = i * 256 + tid;
            const int f4  = flat & 7;
            const int key = (flat >> 3) & 63;
            const int p   = (flat >> 9) & 1;
            const int dh  = flat >> 10;
            const float* src = (p ? qkv_i : qkv_r)
                + ((size_t)(ch*64 + key) * BB + b) * NQKV + 2*EE + h * DD + dh*32 + f4*4;
            const float4 v = *(const float4*)src;
            char* vb = (char*)&KV[p][0][0];
            const int d0 = dh*32 + f4*4;
            *(f16*)(vb + (((d0+0)*128 + key*2) ^ (((d0+0)&7)<<4))) = (f16)v.x;
            *(f16*)(vb + (((d0+1)*128 + key*2) ^ (((d0+1)&7)<<4))) = (f16)v.y;
            *(f16*)(vb + (((d0+2)*128 + key*2) ^ (((d0+2)&7)<<4))) = (f16)v.z;
            *(f16*)(vb + (((d0+3)*128 + key*2) ^ (((d0+3)&7)<<4))) = (f16)v.w;
        }
        __syncthreads();
        {
            const int drow = wave * 16 + c16;           // d index (A row)
            const int sw = (c16 & 7) << 4;              // (drow&7)==(c16&7)
            const char* v0 = (const char*)&KV[0][0][0];
            const char* v1 = (const char*)&KV[1][0][0];
            #pragma unroll
            for (int s0 = 0; s0 < 64; s0 += 32) {
                const f16x8 vr = *(const f16x8*)(v0 + ((drow*128 + (s0 + g*8)*2) ^ sw));
                const f16x8 vi = *(const f16x8*)(v1 + ((drow*128 + (s0 + g*8)*2) ^ sw));
                const f16x8 nvi = -vi;
                const float* s0p = &S[0][c16][ch*64 + s0 + g*8];
                const float* s1p = &S[1][c16][ch*64 + s0 + g*8];
                const f16x8 awr = cvt8(*(const float4*)s0p, *(const float4*)(s0p + 4));
                const f16x8 awi = cvt8(*(const float4*)s1p, *(const float4*)(s1p + 4));
                pr = MFMA16(vr,  awr, pr, 0,0,0);
                pr = MFMA16(vi,  awi, pr, 0,0,0);
                pi = MFMA16(vr,  awi, pi, 0,0,0);
                pi = MFMA16(nvi, awr, pi, 0,0,0);
            }
        }
        __syncthreads();
    }

    // store attn^T tile: lane holds D[d=wave*16+g*4+rg][q=c16]
    {
        const int d0 = wave * 16 + g * 4;
        const size_t ob = ((size_t)(t0 + c16) * BB + b) * EE + h * DD + d0;
        float4 o;
        o.x = pr[0]; o.y = pr[1]; o.z = pr[2]; o.w = pr[3];
        *(float4*)(attn_r + ob) = o;
        o.x = pi[0]; o.y = pi[1]; o.z = pi[2]; o.w = pi[3];
        *(float4*)(attn_i + ob) = o;
    }
}

// ---------------------------------------------------------------------------
extern "C" void kernel_launch(void* const* d_in, const int* in_sizes, int n_in,
                              void* d_out, int out_size, void* d_ws, size_t ws_size,
                              hipStream_t stream)
{
    const float* query_r = (const float*)d_in[0];
    const float* query_i = (const float*)d_in[1];
    const float* W_qkv_r = (const float*)d_in[2];
    const float* W_qkv_i = (const float*)d_in[3];
    const float* b_qkv_r = (const float*)d_in[4];
    const float* b_qkv_i = (const float*)d_in[5];
    const float* W_out_r = (const float*)d_in[6];
    const float* W_out_i = (const float*)d_in[7];
    const float* b_out_r = (const float*)d_in[8];
    const float* b_out_i = (const float*)d_in[9];

    float* ws = (float*)d_ws;
    float* qkv_r  = ws;
    float* qkv_i  = qkv_r  + (size_t)MM * NQKV;
    float* attn_r = qkv_i  + (size_t)MM * NQKV;
    float* attn_i = attn_r + (size_t)MM * EE;

    float* out   = (float*)d_out;
    float* out_r = out;
    float* out_i = out + (size_t)MM * EE;
    float* aw    = out + 2 * (size_t)MM * EE;            // [2,B,T,T]

    hipMemsetAsync(aw, 0, (size_t)2 * BB * TT * TT * sizeof(float), stream);

    // QKV projection (complex, fp32)
    {
        dim3 grid(NQKV / 64, MM / 64);
        gemm_cplx<<<grid, dim3(256), 0, stream>>>(
            query_r, query_i, W_qkv_r, W_qkv_i, b_qkv_r, b_qkv_i,
            qkv_r, qkv_i, NQKV, EE);
    }
    // fused attention (MFMA f16)
    {
        dim3 grid(TT / 16, HH, BB);
        attn_mfma<<<grid, dim3(256), 0, stream>>>(qkv_r, qkv_i, attn_r, attn_i, aw);
    }
    // output projection (complex, fp32)
    {
        dim3 grid(EE / 64, MM / 64);
        gemm_cplx<<<grid, dim3(256), 0, stream>>>(
            attn_r, attn_i, W_out_r, W_out_i, b_out_r, b_out_i,
            out_r, out_i, EE, EE);
    }
}

// Round 3
// 487.760 us; speedup vs baseline: 15.7654x; 3.7591x over previous
//
#include <hip/hip_runtime.h>
#include <math.h>

#define TT 1024
#define BB 8
#define EE 512
#define HH 8
#define DD 64
#define MM (TT*BB)        // 8192 rows (t*B + b)
#define NQKV (3*EE)       // 1536
#define SCALEF 0.125f     // D^-0.5

typedef _Float16 f16;
typedef f16 f16x8 __attribute__((ext_vector_type(8)));
typedef f16 f16x4 __attribute__((ext_vector_type(4)));
typedef float f32x4 __attribute__((ext_vector_type(4)));

#define MFMA16 __builtin_amdgcn_mfma_f32_16x16x32_f16

// async 16B global->LDS (dest = wave-uniform base + lane*16)
typedef __attribute__((address_space(3))) void lds_t;
typedef const __attribute__((address_space(1))) void gmem_t;
__device__ inline void gld_lds16(const void* g, void* l) {
    __builtin_amdgcn_global_load_lds((gmem_t*)g, (lds_t*)l, 16, 0, 0);
}

// ---------------------------------------------------------------------------
// fp32 -> f16 conversion (pairs)
// ---------------------------------------------------------------------------
__global__ __launch_bounds__(256) void cvt_f16_pair(
    const float* __restrict__ sr, const float* __restrict__ si,
    f16* __restrict__ dr, f16* __restrict__ di, int n4)
{
    const int idx = blockIdx.x * 256 + threadIdx.x;
    if (idx < n4) {
        const float4 a = ((const float4*)sr)[idx];
        const float4 b = ((const float4*)si)[idx];
        f16x4 fa, fb;
        fa[0]=(f16)a.x; fa[1]=(f16)a.y; fa[2]=(f16)a.z; fa[3]=(f16)a.w;
        fb[0]=(f16)b.x; fb[1]=(f16)b.y; fb[2]=(f16)b.z; fb[3]=(f16)b.w;
        ((f16x4*)dr)[idx] = fa;
        ((f16x4*)di)[idx] = fb;
    }
}

// ---------------------------------------------------------------------------
// Complex f16 MFMA GEMM, 128x128 tile, BK=32, 4 waves (2x2), 64x64 per wave.
// X:[M][K] f16, W:[N][K] f16 (row-major, W used as B with col=n).
// Yr = Xr Wr^T - Xi Wi^T + br ; Yi = Xi Wr^T + Xr Wi^T + bi
// ---------------------------------------------------------------------------
__global__ __launch_bounds__(256, 2) void gemm_cplx_f16(
    const f16* __restrict__ Xr, const f16* __restrict__ Xi,
    const f16* __restrict__ Wr, const f16* __restrict__ Wi,
    const float* __restrict__ biasr, const float* __restrict__ biasi,
    void* __restrict__ Yr_, void* __restrict__ Yi_,
    int N, int K, int storef16)
{
    __shared__ __attribute__((aligned(16))) f16 Asr[128][32];
    __shared__ __attribute__((aligned(16))) f16 Asi[128][32];
    __shared__ __attribute__((aligned(16))) f16 Bsr[128][32];
    __shared__ __attribute__((aligned(16))) f16 Bsi[128][32];

    const int tid  = threadIdx.x;
    const int wave = tid >> 6;
    const int lane = tid & 63;
    const int c16  = lane & 15;
    const int g    = lane >> 4;
    const int wm = wave >> 1, wn = wave & 1;
    const int m0 = blockIdx.y * 128;
    const int n0 = blockIdx.x * 128;

    const int srow = tid >> 2;   // staging: 4 lanes per row, 16B each
    const int sseg = tid & 3;

    f32x4 accr[4][4] = {};
    f32x4 acci[4][4] = {};

    for (int k0 = 0; k0 < K; k0 += 32) {
        __syncthreads();
        #pragma unroll
        for (int is = 0; is < 2; ++is) {
            const int row = is * 64 + srow;
            const size_t xb = (size_t)(m0 + row) * K + k0 + sseg * 8;
            const size_t wb = (size_t)(n0 + row) * K + k0 + sseg * 8;
            const int dof = is * 4096 + wave * 1024;
            gld_lds16(Xr + xb, (char*)Asr + dof);
            gld_lds16(Xi + xb, (char*)Asi + dof);
            gld_lds16(Wr + wb, (char*)Bsr + dof);
            gld_lds16(Wi + wb, (char*)Bsi + dof);
        }
        __syncthreads();

        f16x8 a_r[4], a_i[4], na_i[4];
        #pragma unroll
        for (int mi = 0; mi < 4; ++mi) {
            const int row = wm * 64 + mi * 16 + c16;
            a_r[mi] = *(const f16x8*)((const char*)Asr + row * 64 + g * 16);
            a_i[mi] = *(const f16x8*)((const char*)Asi + row * 64 + g * 16);
            na_i[mi] = -a_i[mi];
        }
        #pragma unroll
        for (int ni = 0; ni < 4; ++ni) {
            const int row = wn * 64 + ni * 16 + c16;
            const f16x8 b_r = *(const f16x8*)((const char*)Bsr + row * 64 + g * 16);
            const f16x8 b_i = *(const f16x8*)((const char*)Bsi + row * 64 + g * 16);
            #pragma unroll
            for (int mi = 0; mi < 4; ++mi) {
                accr[mi][ni] = MFMA16(a_r[mi],  b_r, accr[mi][ni], 0,0,0);
                accr[mi][ni] = MFMA16(na_i[mi], b_i, accr[mi][ni], 0,0,0);
                acci[mi][ni] = MFMA16(a_i[mi],  b_r, acci[mi][ni], 0,0,0);
                acci[mi][ni] = MFMA16(a_r[mi],  b_i, acci[mi][ni], 0,0,0);
            }
        }
    }

    float biasR[4], biasI[4];
    #pragma unroll
    for (int ni = 0; ni < 4; ++ni) {
        const int n = n0 + wn * 64 + ni * 16 + c16;
        biasR[ni] = biasr[n];
        biasI[ni] = biasi[n];
    }
    #pragma unroll
    for (int mi = 0; mi < 4; ++mi) {
        #pragma unroll
        for (int ni = 0; ni < 4; ++ni) {
            const int n = n0 + wn * 64 + ni * 16 + c16;
            #pragma unroll
            for (int rg = 0; rg < 4; ++rg) {
                const size_t m = (size_t)(m0 + wm * 64 + mi * 16 + g * 4 + rg);
                const float vr = accr[mi][ni][rg] + biasR[ni];
                const float vi = acci[mi][ni][rg] + biasI[ni];
                if (storef16) {
                    ((f16*)Yr_)[m * N + n] = (f16)vr;
                    ((f16*)Yi_)[m * N + n] = (f16)vi;
                } else {
                    ((float*)Yr_)[m * N + n] = vr;
                    ((float*)Yi_)[m * N + n] = vi;
                }
            }
        }
    }
}

// ---------------------------------------------------------------------------
// Fused complex attention, one block per (b, 16 q-rows), ALL 8 heads.
// 256 threads / 4 waves. LDS: S (f16, swizzled) 64KB + KV staging 16KB.
// Head-averaged aw accumulated in registers, written once (no atomics).
// ---------------------------------------------------------------------------
__global__ __launch_bounds__(256, 2) void attn_mfma2(
    const f16* __restrict__ qkv_r, const f16* __restrict__ qkv_i,
    f16* __restrict__ attn_r, f16* __restrict__ attn_i,
    float* __restrict__ aw_out)
{
    // S[p][q][j] f16 at byte p*32768 + q*2048 + ((j*2) ^ ((q&7)<<4))
    __shared__ __attribute__((aligned(16))) char S[65536];
    // K chunk:  [p][key][d]  byte p*8192 + key*128 + ((d*2) ^ ((key&7)<<4))
    // V chunk:  [p][d][key]  byte p*8192 + d*128 + slot*16 + (key&7)*2,
    //           slot = ((key>>3) ^ ((d>>2)&7) ^ ((d&3)<<1)) & 7
    __shared__ __attribute__((aligned(16))) char KV[16384];

    const int qt = blockIdx.x, b = blockIdx.y;
    const int t0 = qt * 16;
    const int tid = threadIdx.x;
    const int wave = tid >> 6, lane = tid & 63;
    const int c16 = lane & 15, g = lane >> 4;
    const int r = tid >> 4, c = tid & 15;   // softmax row / lane-in-row

    float acc_aw[2][8][8] = {};   // per-thread slice of head-averaged aw

    for (int h = 0; h < HH; ++h) {
        // Q fragments (A operand: row=c16, k=g*8+j)
        const size_t qoff = ((size_t)(t0 + c16) * BB + b) * NQKV + h * DD;
        const f16x8 qr0 = *(const f16x8*)(qkv_r + qoff + g * 8);
        const f16x8 qr1 = *(const f16x8*)(qkv_r + qoff + 32 + g * 8);
        const f16x8 qi0 = *(const f16x8*)(qkv_i + qoff + g * 8);
        const f16x8 qi1 = *(const f16x8*)(qkv_i + qoff + 32 + g * 8);
        const f16x8 nqr0 = -qr0, nqr1 = -qr1;

        // ---------------- Phase A: scores ----------------
        for (int ch = 0; ch < 16; ++ch) {
            __syncthreads();
            #pragma unroll
            for (int p = 0; p < 2; ++p) {
                const f16* sb = p ? qkv_i : qkv_r;
                #pragma unroll
                for (int is = 0; is < 2; ++is) {
                    const int key = is * 32 + (tid >> 3);
                    const int d0 = ((tid & 7) ^ (key & 7)) * 8;  // swizzled source
                    const f16* src = sb + ((size_t)(ch * 64 + key) * BB + b) * NQKV
                                        + EE + h * DD + d0;
                    gld_lds16(src, KV + p * 8192 + is * 4096 + wave * 1024);
                }
            }
            __syncthreads();
            const int krow = wave * 16 + c16;
            const int ksw = (krow & 7) << 4;
            const char* K0 = KV;
            const char* K1 = KV + 8192;
            const f16x8 kr0 = *(const f16x8*)(K0 + krow * 128 + ((     g * 16) ^ ksw));
            const f16x8 kr1 = *(const f16x8*)(K0 + krow * 128 + ((64 + g * 16) ^ ksw));
            const f16x8 ki0 = *(const f16x8*)(K1 + krow * 128 + ((     g * 16) ^ ksw));
            const f16x8 ki1 = *(const f16x8*)(K1 + krow * 128 + ((64 + g * 16) ^ ksw));
            f32x4 sr = {}, si = {};
            sr = MFMA16(qr0, kr0, sr, 0,0,0); sr = MFMA16(qr1, kr1, sr, 0,0,0);
            sr = MFMA16(qi0, ki0, sr, 0,0,0); sr = MFMA16(qi1, ki1, sr, 0,0,0);
            si = MFMA16(qi0, kr0, si, 0,0,0); si = MFMA16(qi1, kr1, si, 0,0,0);
            si = MFMA16(nqr0, ki0, si, 0,0,0); si = MFMA16(nqr1, ki1, si, 0,0,0);
            const int j = ch * 64 + krow;
            #pragma unroll
            for (int rg = 0; rg < 4; ++rg) {
                const int q = g * 4 + rg;
                const int off = q * 2048 + ((j * 2) ^ ((q & 7) << 4));
                *(f16*)(S + off)         = (f16)(sr[rg] * SCALEF);
                *(f16*)(S + 32768 + off) = (f16)(si[rg] * SCALEF);
            }
        }
        __syncthreads();

        // ---------------- Phase B: softmax ----------------
        float inv_[2];
        #pragma unroll
        for (int p = 0; p < 2; ++p) {
            char* Sp = S + p * 32768;
            float m = -1e30f;
            #pragma unroll
            for (int i = 0; i < 8; ++i) {
                const int j = c * 8 + i * 128;
                const f16x8 v = *(const f16x8*)(Sp + r * 2048 + ((j * 2) ^ ((r & 7) << 4)));
                #pragma unroll
                for (int e = 0; e < 8; ++e) m = fmaxf(m, (float)v[e]);
            }
            #pragma unroll
            for (int off = 8; off; off >>= 1) m = fmaxf(m, __shfl_xor(m, off, 16));
            float sum = 0.f;
            #pragma unroll
            for (int i = 0; i < 8; ++i) {
                const int j = c * 8 + i * 128;
                char* ptr = Sp + r * 2048 + ((j * 2) ^ ((r & 7) << 4));
                const f16x8 v = *(const f16x8*)ptr;
                f16x8 ev;
                #pragma unroll
                for (int e = 0; e < 8; ++e) {
                    const float x = __expf((float)v[e] - m);
                    ev[e] = (f16)x;
                    sum += x;
                }
                *(f16x8*)ptr = ev;
            }
            #pragma unroll
            for (int off = 8; off; off >>= 1) sum += __shfl_xor(sum, off, 16);
            inv_[p] = 1.0f / sum;
        }
        // normalize in place + accumulate head-average (registers)
        #pragma unroll
        for (int p = 0; p < 2; ++p) {
            const float inv = inv_[p];
            char* Sp = S + p * 32768;
            #pragma unroll
            for (int i = 0; i < 8; ++i) {
                const int j = c * 8 + i * 128;
                char* ptr = Sp + r * 2048 + ((j * 2) ^ ((r & 7) << 4));
                const f16x8 v = *(const f16x8*)ptr;
                f16x8 av;
                #pragma unroll
                for (int e = 0; e < 8; ++e) {
                    const float a = (float)v[e] * inv;
                    av[e] = (f16)a;
                    acc_aw[p][i][e] += a;
                }
                *(f16x8*)ptr = av;
            }
        }
        __syncthreads();

        // ---------------- Phase C: PV ----------------
        f32x4 pr = {}, pi = {};
        for (int ch = 0; ch < 16; ++ch) {
            // load V regs (global, no LDS yet)
            f16x8 vreg[2][2];
            #pragma unroll
            for (int p = 0; p < 2; ++p) {
                const f16* sb = p ? qkv_i : qkv_r;
                #pragma unroll
                for (int it = 0; it < 2; ++it) {
                    const int slot = it * 256 + tid;
                    const int key = slot >> 3;
                    const int d0 = (slot & 7) * 8;
                    vreg[p][it] = *(const f16x8*)(sb + ((size_t)(ch * 64 + key) * BB + b) * NQKV
                                                    + 2 * EE + h * DD + d0);
                }
            }
            __syncthreads();
            #pragma unroll
            for (int p = 0; p < 2; ++p) {
                char* Vp = KV + p * 8192;
                #pragma unroll
                for (int it = 0; it < 2; ++it) {
                    const int slot = it * 256 + tid;
                    const int key = slot >> 3;
                    const int d0 = (slot & 7) * 8;
                    #pragma unroll
                    for (int e = 0; e < 8; ++e) {
                        const int d = d0 + e;
                        const int sl = (((key >> 3) ^ ((d >> 2) & 7) ^ ((d & 3) << 1)) & 7);
                        *(f16*)(Vp + d * 128 + sl * 16 + (key & 7) * 2) = vreg[p][it][e];
                    }
                }
            }
            __syncthreads();
            const int drow = wave * 16 + c16;
            #pragma unroll
            for (int s0 = 0; s0 < 64; s0 += 32) {
                const int jbase = ch * 64 + s0 + g * 8;
                const int aoff = c16 * 2048 + ((jbase * 2) ^ ((c16 & 7) << 4));
                const f16x8 awr = *(const f16x8*)(S + aoff);
                const f16x8 awi = *(const f16x8*)(S + 32768 + aoff);
                const int slv = (((s0 >> 3) + g) ^ ((drow >> 2) & 7) ^ ((drow & 3) << 1)) & 7;
                const f16x8 vr = *(const f16x8*)(KV + drow * 128 + slv * 16);
                const f16x8 vi = *(const f16x8*)(KV + 8192 + drow * 128 + slv * 16);
                const f16x8 nvi = -vi;
                pr = MFMA16(awr, vr, pr, 0,0,0);
                pr = MFMA16(awi, vi, pr, 0,0,0);
                pi = MFMA16(awi, vr, pi, 0,0,0);
                pi = MFMA16(awr, nvi, pi, 0,0,0);
            }
        }
        // store attn tile: D[q = g*4+rg][d = wave*16+c16]
        #pragma unroll
        for (int rg = 0; rg < 4; ++rg) {
            const int q = g * 4 + rg;
            const int d = wave * 16 + c16;
            const size_t ob = ((size_t)(t0 + q) * BB + b) * EE + h * DD + d;
            attn_r[ob] = (f16)pr[rg];
            attn_i[ob] = (f16)pi[rg];
        }
    }

    // final head-averaged aw write (exclusive rows -> plain coalesced stores)
    #pragma unroll
    for (int p = 0; p < 2; ++p) {
        float* dst = aw_out + (size_t)p * BB * TT * TT + ((size_t)b * TT + t0 + r) * TT;
        #pragma unroll
        for (int i = 0; i < 8; ++i) {
            const int j = c * 8 + i * 128;
            float4 v0, v1;
            v0.x = acc_aw[p][i][0] * 0.125f; v0.y = acc_aw[p][i][1] * 0.125f;
            v0.z = acc_aw[p][i][2] * 0.125f; v0.w = acc_aw[p][i][3] * 0.125f;
            v1.x = acc_aw[p][i][4] * 0.125f; v1.y = acc_aw[p][i][5] * 0.125f;
            v1.z = acc_aw[p][i][6] * 0.125f; v1.w = acc_aw[p][i][7] * 0.125f;
            *(float4*)(dst + j) = v0;
            *(float4*)(dst + j + 4) = v1;
        }
    }
}

// ---------------------------------------------------------------------------
extern "C" void kernel_launch(void* const* d_in, const int* in_sizes, int n_in,
                              void* d_out, int out_size, void* d_ws, size_t ws_size,
                              hipStream_t stream)
{
    const float* query_r = (const float*)d_in[0];
    const float* query_i = (const float*)d_in[1];
    const float* W_qkv_r = (const float*)d_in[2];
    const float* W_qkv_i = (const float*)d_in[3];
    const float* b_qkv_r = (const float*)d_in[4];
    const float* b_qkv_i = (const float*)d_in[5];
    const float* W_out_r = (const float*)d_in[6];
    const float* W_out_i = (const float*)d_in[7];
    const float* b_out_r = (const float*)d_in[8];
    const float* b_out_i = (const float*)d_in[9];

    char* w = (char*)d_ws;
    f16* q16_r = (f16*)(w);
    f16* q16_i = (f16*)(w + 8388608);
    f16* Wq_r  = (f16*)(w + 16777216);
    f16* Wq_i  = (f16*)(w + 18350080);
    f16* Wo_r  = (f16*)(w + 19922944);
    f16* Wo_i  = (f16*)(w + 20447232);
    f16* qkv_r = (f16*)(w + 20971520);
    f16* qkv_i = (f16*)(w + 46137344);
    f16* at_r  = (f16*)(w + 71303168);
    f16* at_i  = (f16*)(w + 79691776);

    float* out   = (float*)d_out;
    float* out_r = out;
    float* out_i = out + (size_t)MM * EE;
    float* aw    = out + 2 * (size_t)MM * EE;   // [2][B][T][T]

    // fp32 -> f16 conversions
    {
        const int n4q = MM * EE / 4;            // 1,048,576
        cvt_f16_pair<<<dim3((n4q + 255) / 256), dim3(256), 0, stream>>>(
            query_r, query_i, q16_r, q16_i, n4q);
        const int n4wq = NQKV * EE / 4;         // 196,608
        cvt_f16_pair<<<dim3((n4wq + 255) / 256), dim3(256), 0, stream>>>(
            W_qkv_r, W_qkv_i, Wq_r, Wq_i, n4wq);
        const int n4wo = EE * EE / 4;           // 65,536
        cvt_f16_pair<<<dim3((n4wo + 255) / 256), dim3(256), 0, stream>>>(
            W_out_r, W_out_i, Wo_r, Wo_i, n4wo);
    }
    // QKV projection (complex f16 MFMA), stores f16
    gemm_cplx_f16<<<dim3(NQKV / 128, MM / 128), dim3(256), 0, stream>>>(
        q16_r, q16_i, Wq_r, Wq_i, b_qkv_r, b_qkv_i,
        (void*)qkv_r, (void*)qkv_i, NQKV, EE, 1);
    // fused attention (all heads per block, register aw-average)
    attn_mfma2<<<dim3(TT / 16, BB), dim3(256), 0, stream>>>(
        qkv_r, qkv_i, at_r, at_i, aw);
    // output projection (complex f16 MFMA), stores f32 to d_out
    gemm_cplx_f16<<<dim3(EE / 128, MM / 128), dim3(256), 0, stream>>>(
        at_r, at_i, Wo_r, Wo_i, b_out_r, b_out_i,
        (void*)out_r, (void*)out_i, EE, EE, 0);
}

// Round 5
// 459.125 us; speedup vs baseline: 16.7487x; 1.0624x over previous
//
#include <hip/hip_runtime.h>
#include <math.h>

#define TT 1024
#define BB 8
#define EE 512
#define HH 8
#define DD 64
#define MM (TT*BB)        // 8192 rows (t*B + b)
#define NQKV (3*EE)       // 1536
#define SCALEF 0.125f     // D^-0.5

typedef _Float16 f16;
typedef f16 f16x8 __attribute__((ext_vector_type(8)));
typedef f16 f16x4 __attribute__((ext_vector_type(4)));
typedef float f32x4 __attribute__((ext_vector_type(4)));

#define MFMA16 __builtin_amdgcn_mfma_f32_16x16x32_f16

// async 16B global->LDS (dest = wave-uniform base + lane*16)
typedef __attribute__((address_space(3))) void lds_t;
typedef const __attribute__((address_space(1))) void gmem_t;
__device__ inline void gld_lds16(const void* g, void* l) {
    __builtin_amdgcn_global_load_lds((gmem_t*)g, (lds_t*)l, 16, 0, 0);
}

// hardware transpose read. Semantics (m156/m162): tile = addr & ~127,
// column = addr bits [6:3]; elem j = element (col + j*16) of the 4x16 f16
// tile. Canonical per-lane addr = base + lane*8 -> lane reads column
// (lane&15) of tile (lane>>4).
typedef const __attribute__((address_space(3))) f16 lds_cf16;
__device__ inline f16x4 tr16(const void* p) {
    f16x4 d;
    asm volatile("ds_read_b64_tr_b16 %0, %1" : "=v"(d) : "v"((lds_cf16*)p));
    return d;
}

// ---------------------------------------------------------------------------
// fp32 -> f16 conversion (pairs)
// ---------------------------------------------------------------------------
__global__ __launch_bounds__(256) void cvt_f16_pair(
    const float* __restrict__ sr, const float* __restrict__ si,
    f16* __restrict__ dr, f16* __restrict__ di, int n4)
{
    const int idx = blockIdx.x * 256 + threadIdx.x;
    if (idx < n4) {
        const float4 a = ((const float4*)sr)[idx];
        const float4 b = ((const float4*)si)[idx];
        f16x4 fa, fb;
        fa[0]=(f16)a.x; fa[1]=(f16)a.y; fa[2]=(f16)a.z; fa[3]=(f16)a.w;
        fb[0]=(f16)b.x; fb[1]=(f16)b.y; fb[2]=(f16)b.z; fb[3]=(f16)b.w;
        ((f16x4*)dr)[idx] = fa;
        ((f16x4*)di)[idx] = fb;
    }
}

// ---------------------------------------------------------------------------
// Complex f16 MFMA GEMM, 128x128 tile, BK=32, 4 waves (2x2), 64x64 per wave.
// ---------------------------------------------------------------------------
__global__ __launch_bounds__(256, 2) void gemm_cplx_f16(
    const f16* __restrict__ Xr, const f16* __restrict__ Xi,
    const f16* __restrict__ Wr, const f16* __restrict__ Wi,
    const float* __restrict__ biasr, const float* __restrict__ biasi,
    void* __restrict__ Yr_, void* __restrict__ Yi_,
    int N, int K, int storef16)
{
    __shared__ __attribute__((aligned(16))) f16 Asr[128][32];
    __shared__ __attribute__((aligned(16))) f16 Asi[128][32];
    __shared__ __attribute__((aligned(16))) f16 Bsr[128][32];
    __shared__ __attribute__((aligned(16))) f16 Bsi[128][32];

    const int tid  = threadIdx.x;
    const int wave = tid >> 6;
    const int lane = tid & 63;
    const int c16  = lane & 15;
    const int g    = lane >> 4;
    const int wm = wave >> 1, wn = wave & 1;
    const int m0 = blockIdx.y * 128;
    const int n0 = blockIdx.x * 128;

    const int srow = tid >> 2;
    const int sseg = tid & 3;

    f32x4 accr[4][4] = {};
    f32x4 acci[4][4] = {};

    for (int k0 = 0; k0 < K; k0 += 32) {
        __syncthreads();
        #pragma unroll
        for (int is = 0; is < 2; ++is) {
            const int row = is * 64 + srow;
            const size_t xb = (size_t)(m0 + row) * K + k0 + sseg * 8;
            const size_t wb = (size_t)(n0 + row) * K + k0 + sseg * 8;
            const int dof = is * 4096 + wave * 1024;
            gld_lds16(Xr + xb, (char*)Asr + dof);
            gld_lds16(Xi + xb, (char*)Asi + dof);
            gld_lds16(Wr + wb, (char*)Bsr + dof);
            gld_lds16(Wi + wb, (char*)Bsi + dof);
        }
        __syncthreads();

        f16x8 a_r[4], a_i[4], na_i[4];
        #pragma unroll
        for (int mi = 0; mi < 4; ++mi) {
            const int row = wm * 64 + mi * 16 + c16;
            a_r[mi] = *(const f16x8*)((const char*)Asr + row * 64 + g * 16);
            a_i[mi] = *(const f16x8*)((const char*)Asi + row * 64 + g * 16);
            na_i[mi] = -a_i[mi];
        }
        #pragma unroll
        for (int ni = 0; ni < 4; ++ni) {
            const int row = wn * 64 + ni * 16 + c16;
            const f16x8 b_r = *(const f16x8*)((const char*)Bsr + row * 64 + g * 16);
            const f16x8 b_i = *(const f16x8*)((const char*)Bsi + row * 64 + g * 16);
            #pragma unroll
            for (int mi = 0; mi < 4; ++mi) {
                accr[mi][ni] = MFMA16(a_r[mi],  b_r, accr[mi][ni], 0,0,0);
                accr[mi][ni] = MFMA16(na_i[mi], b_i, accr[mi][ni], 0,0,0);
                acci[mi][ni] = MFMA16(a_i[mi],  b_r, acci[mi][ni], 0,0,0);
                acci[mi][ni] = MFMA16(a_r[mi],  b_i, acci[mi][ni], 0,0,0);
            }
        }
    }

    float biasR[4], biasI[4];
    #pragma unroll
    for (int ni = 0; ni < 4; ++ni) {
        const int n = n0 + wn * 64 + ni * 16 + c16;
        biasR[ni] = biasr[n];
        biasI[ni] = biasi[n];
    }
    #pragma unroll
    for (int mi = 0; mi < 4; ++mi) {
        #pragma unroll
        for (int ni = 0; ni < 4; ++ni) {
            const int n = n0 + wn * 64 + ni * 16 + c16;
            #pragma unroll
            for (int rg = 0; rg < 4; ++rg) {
                const size_t m = (size_t)(m0 + wm * 64 + mi * 16 + g * 4 + rg);
                const float vr = accr[mi][ni][rg] + biasR[ni];
                const float vi = acci[mi][ni][rg] + biasI[ni];
                if (storef16) {
                    ((f16*)Yr_)[m * N + n] = (f16)vr;
                    ((f16*)Yi_)[m * N + n] = (f16)vi;
                } else {
                    ((float*)Yr_)[m * N + n] = vr;
                    ((float*)Yi_)[m * N + n] = vi;
                }
            }
        }
    }
}

// ---------------------------------------------------------------------------
// Fused complex attention v3 (tr-read address fixed).
// Block = (b, 16 q-rows), all 8 heads, 256 threads / 4 waves.
// Phase A: K fragments direct global->reg (no LDS, no barriers), MFMA -> S f16.
// Phase B: exact softmax on S, acc_aw accumulated in registers.
// Phase C: V staged per-32-key-half via global_load_lds into subtiled layout
//          [dblk=wave][key][16], consumed with ds_read_b64_tr_b16; 2-slot ring,
//          loads for half h+1 issued under compute of half h.
// ---------------------------------------------------------------------------
__global__ __launch_bounds__(256, 2) void attn_mfma3(
    const f16* __restrict__ qkv_r, const f16* __restrict__ qkv_i,
    f16* __restrict__ attn_r, f16* __restrict__ attn_i,
    float* __restrict__ aw_out)
{
    // S[p][q][j] f16 at byte p*32768 + q*2048 + ((j*2) ^ ((q&7)<<4))
    __shared__ __attribute__((aligned(16))) char S[65536];
    // V ring: slot*8192 + p*4096 + wave*1024 + key*32 + dl*2 (key<32, dl<16)
    __shared__ __attribute__((aligned(16))) char KV[16384];

    const int qt = blockIdx.x, b = blockIdx.y;
    const int t0 = qt * 16;
    const int tid = threadIdx.x;
    const int wave = tid >> 6, lane = tid & 63;
    const int c16 = lane & 15, g = lane >> 4;
    const int r = tid >> 4, c = tid & 15;   // softmax row / lane-in-row

    float acc_aw[2][8][8] = {};   // per-thread slice of head-averaged aw

    // V staging source coords for this lane (dest is lane*16 within wave's KB)
    const int vkey = (lane >> 1) & 31;
    const int vdl  = (lane & 1) * 8;

    for (int h = 0; h < HH; ++h) {
        // ---- Q fragments (A operand: row=c16, k=g*8+j)
        const size_t qoff = ((size_t)(t0 + c16) * BB + b) * NQKV + h * DD;
        const f16x8 qr0 = *(const f16x8*)(qkv_r + qoff + g * 8);
        const f16x8 qr1 = *(const f16x8*)(qkv_r + qoff + 32 + g * 8);
        const f16x8 qi0 = *(const f16x8*)(qkv_i + qoff + g * 8);
        const f16x8 qi1 = *(const f16x8*)(qkv_i + qoff + 32 + g * 8);
        const f16x8 nqr0 = -qr0, nqr1 = -qr1;

        // ---------------- Phase A: scores (no LDS staging, no barriers) -----
        #pragma unroll 2
        for (int ch = 0; ch < 16; ++ch) {
            const int key = ch * 64 + wave * 16 + c16;      // B operand col
            const size_t kb = ((size_t)key * BB + b) * NQKV + EE + h * DD;
            const f16x8 kr0 = *(const f16x8*)(qkv_r + kb + g * 8);
            const f16x8 kr1 = *(const f16x8*)(qkv_r + kb + 32 + g * 8);
            const f16x8 ki0 = *(const f16x8*)(qkv_i + kb + g * 8);
            const f16x8 ki1 = *(const f16x8*)(qkv_i + kb + 32 + g * 8);
            f32x4 sr = {}, si = {};
            sr = MFMA16(qr0, kr0, sr, 0,0,0); sr = MFMA16(qr1, kr1, sr, 0,0,0);
            sr = MFMA16(qi0, ki0, sr, 0,0,0); sr = MFMA16(qi1, ki1, sr, 0,0,0);
            si = MFMA16(qi0, kr0, si, 0,0,0); si = MFMA16(qi1, kr1, si, 0,0,0);
            si = MFMA16(nqr0, ki0, si, 0,0,0); si = MFMA16(nqr1, ki1, si, 0,0,0);
            #pragma unroll
            for (int rg = 0; rg < 4; ++rg) {                // C/D: row=g*4+rg, col=c16
                const int q = g * 4 + rg;
                const int off = q * 2048 + ((key * 2) ^ ((q & 7) << 4));
                *(f16*)(S + off)         = (f16)(sr[rg] * SCALEF);
                *(f16*)(S + 32768 + off) = (f16)(si[rg] * SCALEF);
            }
        }
        __syncthreads();

        // prefetch V half 0 (slot 0) under the softmax
        {
            const size_t vb = ((size_t)vkey * BB + b) * NQKV + 2 * EE + h * DD
                            + wave * 16 + vdl;
            gld_lds16(qkv_r + vb, KV + wave * 1024);
            gld_lds16(qkv_i + vb, KV + 4096 + wave * 1024);
        }

        // ---------------- Phase B: softmax + head-avg accumulate ------------
        #pragma unroll
        for (int p = 0; p < 2; ++p) {
            char* Sp = S + p * 32768;
            const int sw = (r & 7) << 4;
            float m = -1e30f;
            #pragma unroll
            for (int i = 0; i < 8; ++i) {
                const int j = c * 8 + i * 128;
                const f16x8 v = *(const f16x8*)(Sp + r * 2048 + ((j * 2) ^ sw));
                #pragma unroll
                for (int e = 0; e < 8; ++e) m = fmaxf(m, (float)v[e]);
            }
            #pragma unroll
            for (int off = 8; off; off >>= 1) m = fmaxf(m, __shfl_xor(m, off, 16));
            float sum = 0.f;
            #pragma unroll
            for (int i = 0; i < 8; ++i) {
                const int j = c * 8 + i * 128;
                char* ptr = Sp + r * 2048 + ((j * 2) ^ sw);
                const f16x8 v = *(const f16x8*)ptr;
                f16x8 ev;
                #pragma unroll
                for (int e = 0; e < 8; ++e) {
                    const float x = __expf((float)v[e] - m);
                    ev[e] = (f16)x;
                    sum += x;
                }
                *(f16x8*)ptr = ev;
            }
            #pragma unroll
            for (int off = 8; off; off >>= 1) sum += __shfl_xor(sum, off, 16);
            const float inv = 1.0f / sum;
            #pragma unroll
            for (int i = 0; i < 8; ++i) {
                const int j = c * 8 + i * 128;
                char* ptr = Sp + r * 2048 + ((j * 2) ^ sw);
                const f16x8 v = *(const f16x8*)ptr;
                f16x8 av;
                #pragma unroll
                for (int e = 0; e < 8; ++e) {
                    const float a = (float)v[e] * inv;
                    av[e] = (f16)a;
                    acc_aw[p][i][e] += a;
                }
                *(f16x8*)ptr = av;
            }
        }
        __syncthreads();

        // ---------------- Phase C: PV via tr-reads, 32-key halves -----------
        f32x4 pr = {}, pi = {};
        for (int hf = 0; hf < 32; ++hf) {
            asm volatile("s_waitcnt vmcnt(0)");
            __syncthreads();                       // half hf staged & published
            if (hf < 31) {                         // issue half hf+1 into other slot
                const int slot2 = (hf + 1) & 1;
                const size_t vb = ((size_t)((hf + 1) * 32 + vkey) * BB + b) * NQKV
                                + 2 * EE + h * DD + wave * 16 + vdl;
                gld_lds16(qkv_r + vb, KV + slot2 * 8192 + wave * 1024);
                gld_lds16(qkv_i + vb, KV + slot2 * 8192 + 4096 + wave * 1024);
            }
            // compute half hf; tr-read addr = wave block + lane*8
            const int slot = hf & 1;
            const char* vbase = KV + slot * 8192 + wave * 1024 + g * 128 + c16 * 8;
            const f16x4 vr_lo = tr16(vbase);
            const f16x4 vr_hi = tr16(vbase + 512);
            const f16x4 vi_lo = tr16(vbase + 4096);
            const f16x4 vi_hi = tr16(vbase + 4096 + 512);
            const int j0 = hf * 32 + g * 4;
            const int arow = c16 * 2048;
            const int asw = (c16 & 7) << 4;
            const f16x4 arlo = *(const f16x4*)(S + arow + ((j0 * 2) ^ asw));
            const f16x4 arhi = *(const f16x4*)(S + arow + (((j0 + 16) * 2) ^ asw));
            const f16x4 ailo = *(const f16x4*)(S + 32768 + arow + ((j0 * 2) ^ asw));
            const f16x4 aihi = *(const f16x4*)(S + 32768 + arow + (((j0 + 16) * 2) ^ asw));
            asm volatile("s_waitcnt lgkmcnt(0)");
            __builtin_amdgcn_sched_barrier(0);
            const f16x8 vr8 = __builtin_shufflevector(vr_lo, vr_hi, 0,1,2,3,4,5,6,7);
            const f16x8 vi8 = __builtin_shufflevector(vi_lo, vi_hi, 0,1,2,3,4,5,6,7);
            const f16x8 nvi8 = -vi8;
            const f16x8 awr = __builtin_shufflevector(arlo, arhi, 0,1,2,3,4,5,6,7);
            const f16x8 awi = __builtin_shufflevector(ailo, aihi, 0,1,2,3,4,5,6,7);
            pr = MFMA16(awr, vr8,  pr, 0,0,0);
            pr = MFMA16(awi, vi8,  pr, 0,0,0);
            pi = MFMA16(awi, vr8,  pi, 0,0,0);
            pi = MFMA16(awr, nvi8, pi, 0,0,0);
        }
        __syncthreads();   // protect S & KV before next head overwrites

        // store attn tile: lane holds D[q=g*4+rg][d=wave*16+c16]
        #pragma unroll
        for (int rg = 0; rg < 4; ++rg) {
            const int q = g * 4 + rg;
            const int d = wave * 16 + c16;
            const size_t ob = ((size_t)(t0 + q) * BB + b) * EE + h * DD + d;
            attn_r[ob] = (f16)pr[rg];
            attn_i[ob] = (f16)pi[rg];
        }
    }

    // final head-averaged aw write (exclusive rows -> plain coalesced stores)
    #pragma unroll
    for (int p = 0; p < 2; ++p) {
        float* dst = aw_out + (size_t)p * BB * TT * TT + ((size_t)b * TT + t0 + r) * TT;
        #pragma unroll
        for (int i = 0; i < 8; ++i) {
            const int j = c * 8 + i * 128;
            float4 v0, v1;
            v0.x = acc_aw[p][i][0] * 0.125f; v0.y = acc_aw[p][i][1] * 0.125f;
            v0.z = acc_aw[p][i][2] * 0.125f; v0.w = acc_aw[p][i][3] * 0.125f;
            v1.x = acc_aw[p][i][4] * 0.125f; v1.y = acc_aw[p][i][5] * 0.125f;
            v1.z = acc_aw[p][i][6] * 0.125f; v1.w = acc_aw[p][i][7] * 0.125f;
            *(float4*)(dst + j) = v0;
            *(float4*)(dst + j + 4) = v1;
        }
    }
}

// ---------------------------------------------------------------------------
extern "C" void kernel_launch(void* const* d_in, const int* in_sizes, int n_in,
                              void* d_out, int out_size, void* d_ws, size_t ws_size,
                              hipStream_t stream)
{
    const float* query_r = (const float*)d_in[0];
    const float* query_i = (const float*)d_in[1];
    const float* W_qkv_r = (const float*)d_in[2];
    const float* W_qkv_i = (const float*)d_in[3];
    const float* b_qkv_r = (const float*)d_in[4];
    const float* b_qkv_i = (const float*)d_in[5];
    const float* W_out_r = (const float*)d_in[6];
    const float* W_out_i = (const float*)d_in[7];
    const float* b_out_r = (const float*)d_in[8];
    const float* b_out_i = (const float*)d_in[9];

    char* w = (char*)d_ws;
    f16* q16_r = (f16*)(w);
    f16* q16_i = (f16*)(w + 8388608);
    f16* Wq_r  = (f16*)(w + 16777216);
    f16* Wq_i  = (f16*)(w + 18350080);
    f16* Wo_r  = (f16*)(w + 19922944);
    f16* Wo_i  = (f16*)(w + 20447232);
    f16* qkv_r = (f16*)(w + 20971520);
    f16* qkv_i = (f16*)(w + 46137344);
    f16* at_r  = (f16*)(w + 71303168);
    f16* at_i  = (f16*)(w + 79691776);

    float* out   = (float*)d_out;
    float* out_r = out;
    float* out_i = out + (size_t)MM * EE;
    float* aw    = out + 2 * (size_t)MM * EE;   // [2][B][T][T]

    // fp32 -> f16 conversions
    {
        const int n4q = MM * EE / 4;
        cvt_f16_pair<<<dim3((n4q + 255) / 256), dim3(256), 0, stream>>>(
            query_r, query_i, q16_r, q16_i, n4q);
        const int n4wq = NQKV * EE / 4;
        cvt_f16_pair<<<dim3((n4wq + 255) / 256), dim3(256), 0, stream>>>(
            W_qkv_r, W_qkv_i, Wq_r, Wq_i, n4wq);
        const int n4wo = EE * EE / 4;
        cvt_f16_pair<<<dim3((n4wo + 255) / 256), dim3(256), 0, stream>>>(
            W_out_r, W_out_i, Wo_r, Wo_i, n4wo);
    }
    // QKV projection (complex f16 MFMA), stores f16
    gemm_cplx_f16<<<dim3(NQKV / 128, MM / 128), dim3(256), 0, stream>>>(
        q16_r, q16_i, Wq_r, Wq_i, b_qkv_r, b_qkv_i,
        (void*)qkv_r, (void*)qkv_i, NQKV, EE, 1);
    // fused attention
    attn_mfma3<<<dim3(TT / 16, BB), dim3(256), 0, stream>>>(
        qkv_r, qkv_i, at_r, at_i, aw);
    // output projection (complex f16 MFMA), stores f32 to d_out
    gemm_cplx_f16<<<dim3(EE / 128, MM / 128), dim3(256), 0, stream>>>(
        at_r, at_i, Wo_r, Wo_i, b_out_r, b_out_i,
        (void*)out_r, (void*)out_i, EE, EE, 0);
}